// Round 12
// baseline (677.484 us; speedup 1.0000x reference)
//
#include <hip/hip_runtime.h>
#include <hip/hip_cooperative_groups.h>

namespace cg = cooperative_groups;

#define H 128
#define LSTRIDE 136   // LDS row stride in bf16 elems: 272B, 16B-aligned, 2-way bank (free)
#define PSTR 132      // pool stride in floats: rl*132 -> bank offset rl*4, 2-way (free)
typedef unsigned int uint32;
typedef unsigned short u16;
typedef __attribute__((ext_vector_type(8))) short bf16x8;
typedef __attribute__((ext_vector_type(4))) float f32x4;

static __device__ __forceinline__ u16 f2bf(float f){
  uint32 u = __float_as_uint(f);
  uint32 r = (u + 0x7fff + ((u >> 16) & 1)) >> 16;   // RNE bf16 (finite values)
  return (u16)r;
}
static __device__ __forceinline__ float bflo(uint32 u){ return __uint_as_float(u << 16); }
static __device__ __forceinline__ float bfhi(uint32 u){ return __uint_as_float(u & 0xffff0000u); }

// Fused aggregate + MFMA dense phase (16 nodes per block-iteration, 16 lanes/node, unroll-8 gather).
// POOL=0: yout = bf16(dinv*relu(aW+b)) via LDS-staged coalesced store.
// POOL=1: relu(aW+b) -> LDS tile -> parallel segmented atomicAdd into gsum.
template<int POOL>
static __device__ void aggdense_phase(const u16* __restrict__ y, const int* __restrict__ start,
      const int* __restrict__ deg, const u16* __restrict__ csr, const float* __restrict__ dinv,
      const u16* __restrict__ wp, const float* __restrict__ bias,
      u16* __restrict__ yout, const int* __restrict__ batch, float* __restrict__ gsum, int n,
      unsigned short* As, float* poolbuf, int* sbatch)
{
  int tid = threadIdx.x;
  unsigned short* outs = (unsigned short*)poolbuf;
  int ngrp = (n + 15) >> 4;
  for (int grp = blockIdx.x; grp < ngrp; grp += gridDim.x){
    int node16 = grp << 4;
    int nl = tid >> 4;
    int node = node16 + nl;
    int f8 = (tid & 15) * 8;

    // phase A: aggregate
    float a0=0,a1=0,a2=0,a3=0,a4=0,a5=0,a6=0,a7=0;
    float dn = 0.f;
    #define ADDU(u) { a0+=bflo(u.x); a1+=bfhi(u.x); a2+=bflo(u.y); a3+=bfhi(u.y); \
                      a4+=bflo(u.z); a5+=bfhi(u.z); a6+=bflo(u.w); a7+=bfhi(u.w); }
    if (node < n){
      int lo = start[node];
      int hi = lo + deg[node] + 1;
      int e = lo;
      for (; e+8 <= hi; e += 8){
        int s0=csr[e],   s1=csr[e+1], s2=csr[e+2], s3=csr[e+3];
        int s4=csr[e+4], s5=csr[e+5], s6=csr[e+6], s7=csr[e+7];
        uint4 u0 = *(const uint4*)&y[(size_t)s0*H + f8];
        uint4 u1 = *(const uint4*)&y[(size_t)s1*H + f8];
        uint4 u2 = *(const uint4*)&y[(size_t)s2*H + f8];
        uint4 u3 = *(const uint4*)&y[(size_t)s3*H + f8];
        uint4 u4 = *(const uint4*)&y[(size_t)s4*H + f8];
        uint4 u5 = *(const uint4*)&y[(size_t)s5*H + f8];
        uint4 u6 = *(const uint4*)&y[(size_t)s6*H + f8];
        uint4 u7 = *(const uint4*)&y[(size_t)s7*H + f8];
        ADDU(u0); ADDU(u1); ADDU(u2); ADDU(u3);
        ADDU(u4); ADDU(u5); ADDU(u6); ADDU(u7);
      }
      for (; e < hi; e++){
        int s = csr[e];
        uint4 u = *(const uint4*)&y[(size_t)s*H + f8];
        ADDU(u);
      }
      dn = dinv[node];
    }
    #undef ADDU
    uint4 o;
    o.x = (uint32)f2bf(a0*dn) | ((uint32)f2bf(a1*dn) << 16);
    o.y = (uint32)f2bf(a2*dn) | ((uint32)f2bf(a3*dn) << 16);
    o.z = (uint32)f2bf(a4*dn) | ((uint32)f2bf(a5*dn) << 16);
    o.w = (uint32)f2bf(a6*dn) | ((uint32)f2bf(a7*dn) << 16);
    *(uint4*)&As[nl*LSTRIDE + f8] = o;
    __syncthreads();                      // sync #1: As ready (also fences prev-iter epilogue reads)
    if (POOL && tid < 16) sbatch[tid] = (node16 + tid < n) ? batch[node16 + tid] : -1;

    // phase B: MFMA — wave w handles col-tiles {2w, 2w+1}
    int wave = tid >> 6;
    int lane = tid & 63;
    int m = lane & 15, quad = lane >> 4;
    f32x4 acc0 = {0.f,0.f,0.f,0.f}, acc1 = {0.f,0.f,0.f,0.f};
    int ct0 = wave*2, ct1 = wave*2 + 1;
    #pragma unroll
    for (int kt = 0; kt < 4; kt++){
      bf16x8 af = *(const bf16x8*)&As[m*LSTRIDE + kt*32 + quad*8];
      bf16x8 b0 = *(const bf16x8*)&wp[(size_t)((kt*8+ct0)*64 + lane)*8];
      bf16x8 b1 = *(const bf16x8*)&wp[(size_t)((kt*8+ct1)*64 + lane)*8];
      acc0 = __builtin_amdgcn_mfma_f32_16x16x32_bf16(af, b0, acc0, 0, 0, 0);
      acc1 = __builtin_amdgcn_mfma_f32_16x16x32_bf16(af, b1, acc1, 0, 0, 0);
    }
    // C/D layout: col = ct*16 + m, row (in tile) = quad*4 + r
    #pragma unroll
    for (int j = 0; j < 2; j++){
      int ct = wave*2 + j;
      int col = ct*16 + m;
      float bv = bias[col];
      f32x4 ac = j ? acc1 : acc0;
      #pragma unroll
      for (int r = 0; r < 4; r++){
        int rl = quad*4 + r;
        int orow = node16 + rl;
        if (orow < n){
          float v = fmaxf(ac[r] + bv, 0.f);
          if (POOL) poolbuf[rl*PSTR + col] = v;
          else      outs[rl*PSTR + col] = f2bf(v * dinv[orow]);
        }
      }
    }
    __syncthreads();                      // sync #2: tile staged
    if (POOL){
      int col = tid & 127;
      int half = tid >> 7;
      float run = 0.f; int gprev = -1;
      for (int r = half*8; r < half*8 + 8; r++){
        int g = sbatch[r];
        if (g < 0) break;
        if (g != gprev){
          if (gprev >= 0) atomicAdd(&gsum[gprev*H + col], run);
          run = 0.f; gprev = g;
        }
        run += poolbuf[r*PSTR + col];
      }
      if (gprev >= 0) atomicAdd(&gsum[gprev*H + col], run);
    } else {
      int row = tid >> 4;
      int orow = node16 + row;
      if (orow < n){
        const unsigned short* sp = &outs[row*PSTR + f8];
        uint4 v;
        v.x = (uint32)sp[0] | ((uint32)sp[1] << 16);
        v.y = (uint32)sp[2] | ((uint32)sp[3] << 16);
        v.z = (uint32)sp[4] | ((uint32)sp[5] << 16);
        v.w = (uint32)sp[6] | ((uint32)sp[7] << 16);
        *(uint4*)&yout[(size_t)orow*H + f8] = v;
      }
    }
    // no trailing sync needed: next-iter As/pool writes are ordered behind sync #1/#2 of next iter
  }
}

__global__ __launch_bounds__(256, 4) void k_mega(
    const float* __restrict__ pos, const int* __restrict__ ei, const int* __restrict__ batch,
    const float* __restrict__ W1, const float* __restrict__ b1,
    const float* __restrict__ W2, const float* __restrict__ b2,
    const float* __restrict__ W3, const float* __restrict__ b3,
    const float* __restrict__ Wl1, const float* __restrict__ bl1,
    const float* __restrict__ Wl2, const float* __restrict__ bl2, float* __restrict__ out,
    int n, int E, int G,
    int* __restrict__ deg, u16* __restrict__ rank, int* __restrict__ start,
    float* __restrict__ dinv, int* __restrict__ alloc_ctr,
    int* __restrict__ gb, float* __restrict__ gsum, u16* __restrict__ csr, float4* __restrict__ y0,
    u16* __restrict__ ybufA, u16* __restrict__ ybufB, u16* __restrict__ wp2, u16* __restrict__ wp3)
{
  __shared__ unsigned short As[16*LSTRIDE];   // 4352 B
  __shared__ float poolbuf[16*PSTR];          // 8448 B (outs aliases this in non-POOL phase)
  __shared__ int sbatch[16];
  __shared__ float gs[H];
  __shared__ float h1[64];

  cg::grid_group gridg = cg::this_grid();
  int tid = threadIdx.x;
  int gtid = blockIdx.x*256 + tid;
  int gstride = gridDim.x*256;
  const int* src = ei;
  const int* dst = ei + E;

  // ---- phase 0: setup (deg=0, gsum=0, gb, alloc_ctr=0, W2/W3 -> MFMA B-frag bf16) ----
  for (int i = gtid; i < n; i += gstride) deg[i] = 0;
  for (int i = gtid; i < G*H; i += gstride) gsum[i] = 0.f;
  for (int g = gtid; g <= G; g += gstride){
    int lo = 0, hi = n;
    while (lo < hi){ int mm = (lo + hi) >> 1; if (batch[mm] < g) lo = mm + 1; else hi = mm; }
    gb[g] = lo;
  }
  if (gtid == 0) *alloc_ctr = 0;
  for (int g = gtid; g < 4096; g += gstride){
    const float* W = (g < 2048) ? W2 : W3;
    u16* wp = (g < 2048) ? wp2 : wp3;
    int t2 = g & 2047;
    int frag = t2 >> 6, lane = t2 & 63;
    int kt = frag >> 3, ct = frag & 7;
    int m = lane & 15, quad = lane >> 4;
    const float* wrow = &W[(kt*32 + quad*8)*H + ct*16 + m];
    u16 v[8];
    #pragma unroll
    for (int j = 0; j < 8; j++) v[j] = f2bf(wrow[j*H]);
    uint4 o;
    o.x = (uint32)v[0] | ((uint32)v[1] << 16);
    o.y = (uint32)v[2] | ((uint32)v[3] << 16);
    o.z = (uint32)v[4] | ((uint32)v[5] << 16);
    o.w = (uint32)v[6] | ((uint32)v[7] << 16);
    *(uint4*)&wp[(size_t)t2*8] = o;
  }
  gridg.sync();

  // ---- phase 1: in-degree count + per-edge rank ----
  for (int i = gtid; i < E; i += gstride) rank[i] = (u16)atomicAdd(&deg[dst[i]], 1);
  gridg.sync();

  // ---- phase 2: CSR bucket-start via wave-aggregated atomic alloc; dinv; y0 prescale ----
  {
    int lane = tid & 63;
    for (int i = gtid; (i - lane) < n; i += gstride){
      int d = (i < n) ? deg[i] + 1 : 0;     // +1 self-loop
      int pre = d;
      #pragma unroll
      for (int o = 1; o < 64; o <<= 1){
        int v = __shfl_up(pre, o);
        if (lane >= o) pre += v;
      }
      int tot = __shfl(pre, 63);
      int base = 0;
      if (lane == 63 && tot > 0) base = atomicAdd(alloc_ctr, tot);
      base = __shfl(base, 63);
      if (i < n){
        start[i] = base + pre - d;
        float dv = rsqrtf((float)d);
        dinv[i] = dv;
        y0[i] = make_float4(pos[3*i]*dv, pos[3*i+1]*dv, pos[3*i+2]*dv, 0.f);
      }
    }
  }
  gridg.sync();

  // ---- phase 3: atomic-free CSR fill (ushort payload); self-loop at bucket slot 0 ----
  for (int i = gtid; i < E + n; i += gstride){
    if (i < E) csr[start[dst[i]] + 1 + rank[i]] = (u16)src[i];
    else { int j = i - E; csr[start[j]] = (u16)j; }
  }
  gridg.sync();

  // ---- phase 4: layer 1 (3-wide gather + fused 3->128 dense, wave-uniform W1/b1) ----
  for (int node = gtid; node < n; node += gstride){
    int lo = start[node], hi = lo + deg[node] + 1;
    float x=0.f, y=0.f, z=0.f;
    int e = lo;
    for (; e+2 <= hi; e += 2){
      int s0 = csr[e], s1 = csr[e+1];
      float4 v0 = y0[s0], v1 = y0[s1];
      x += v0.x + v1.x; y += v0.y + v1.y; z += v0.z + v1.z;
    }
    if (e < hi){ float4 v = y0[csr[e]]; x += v.x; y += v.y; z += v.z; }
    float dn = dinv[node];
    x *= dn; y *= dn; z *= dn;
    u16* rowp = &ybufA[(size_t)node*H];
    for (int c8 = 0; c8 < 16; c8++){
      float4 wa0 = *(const float4*)&W1[c8*8];
      float4 wa1 = *(const float4*)&W1[c8*8+4];
      float4 wb0 = *(const float4*)&W1[H + c8*8];
      float4 wb1 = *(const float4*)&W1[H + c8*8+4];
      float4 wc0 = *(const float4*)&W1[2*H + c8*8];
      float4 wc1 = *(const float4*)&W1[2*H + c8*8+4];
      float4 bb0 = *(const float4*)&b1[c8*8];
      float4 bb1 = *(const float4*)&b1[c8*8+4];
      float o0 = fmaxf(x*wa0.x + y*wb0.x + z*wc0.x + bb0.x, 0.f) * dn;
      float o1 = fmaxf(x*wa0.y + y*wb0.y + z*wc0.y + bb0.y, 0.f) * dn;
      float o2 = fmaxf(x*wa0.z + y*wb0.z + z*wc0.z + bb0.z, 0.f) * dn;
      float o3 = fmaxf(x*wa0.w + y*wb0.w + z*wc0.w + bb0.w, 0.f) * dn;
      float o4 = fmaxf(x*wa1.x + y*wb1.x + z*wc1.x + bb1.x, 0.f) * dn;
      float o5 = fmaxf(x*wa1.y + y*wb1.y + z*wc1.y + bb1.y, 0.f) * dn;
      float o6 = fmaxf(x*wa1.z + y*wb1.z + z*wc1.z + bb1.z, 0.f) * dn;
      float o7 = fmaxf(x*wa1.w + y*wb1.w + z*wc1.w + bb1.w, 0.f) * dn;
      uint4 o;
      o.x = (uint32)f2bf(o0) | ((uint32)f2bf(o1) << 16);
      o.y = (uint32)f2bf(o2) | ((uint32)f2bf(o3) << 16);
      o.z = (uint32)f2bf(o4) | ((uint32)f2bf(o5) << 16);
      o.w = (uint32)f2bf(o6) | ((uint32)f2bf(o7) << 16);
      *(uint4*)&rowp[c8*8] = o;
    }
  }
  gridg.sync();

  // ---- phase 5: layer 2 (fused aggregate + MFMA) ----
  aggdense_phase<0>(ybufA, start, deg, csr, dinv, wp2, b2, ybufB, (const int*)nullptr, (float*)nullptr, n,
                    As, poolbuf, sbatch);
  gridg.sync();

  // ---- phase 6: layer 3 (fused aggregate + MFMA + mean-pool numerator) ----
  aggdense_phase<1>(ybufB, start, deg, csr, dinv, wp3, b3, (u16*)nullptr, batch, gsum, n,
                    As, poolbuf, sbatch);
  gridg.sync();

  // ---- phase 7: MLP head ----
  for (int g = blockIdx.x; g < G; g += gridDim.x){
    float inv = 1.f / fmaxf((float)(gb[g+1] - gb[g]), 1.f);
    if (tid < H) gs[tid] = gsum[g*H + tid] * inv;
    __syncthreads();
    if (tid < 64){
      float acc = bl1[tid];
      for (int k = 0; k < H; k++) acc += gs[k] * Wl1[k*64 + tid];
      h1[tid] = fmaxf(acc, 0.f);
    }
    __syncthreads();
    if (tid < 10){
      float o = bl2[tid];
      for (int j = 0; j < 64; j++) o += h1[j] * Wl2[j*10 + tid];
      out[g*10 + tid] = o;
    }
    __syncthreads();
  }
}

extern "C" void kernel_launch(void* const* d_in, const int* in_sizes, int n_in,
                              void* d_out, int out_size, void* d_ws, size_t ws_size,
                              hipStream_t stream){
  const float* pos = (const float*)d_in[0];
  const int*  ei   = (const int*)d_in[1];
  const int*  batch= (const int*)d_in[2];
  const float* W1 = (const float*)d_in[3];
  const float* b1 = (const float*)d_in[4];
  const float* W2 = (const float*)d_in[5];
  const float* b2 = (const float*)d_in[6];
  const float* W3 = (const float*)d_in[7];
  const float* b3 = (const float*)d_in[8];
  const float* Wl1 = (const float*)d_in[9];
  const float* bl1 = (const float*)d_in[10];
  const float* Wl2 = (const float*)d_in[11];
  const float* bl2 = (const float*)d_in[12];
  float* out = (float*)d_out;

  int N = in_sizes[0] / 3;     // 50000 (< 65536 required for ushort CSR)
  int E = in_sizes[1] / 2;     // 800000
  int G = out_size / 10;       // 64

  // workspace carve (~30 MB)
  char* p = (char*)d_ws;
  auto carve = [&](size_t bytes)->char* { char* q = p; p += (bytes + 255) & ~(size_t)255; return q; };
  int*    deg       = (int*)   carve(sizeof(int)    * (size_t)N);
  u16*    rank      = (u16*)   carve(sizeof(u16)    * (size_t)E);
  int*    start     = (int*)   carve(sizeof(int)    * (size_t)N);
  float*  dinv      = (float*) carve(sizeof(float)  * (size_t)N);
  int*    alloc_ctr = (int*)   carve(sizeof(int)    * 64);
  int*    gb        = (int*)   carve(sizeof(int)    * (size_t)(G+1));
  float*  gsum      = (float*) carve(sizeof(float)  * (size_t)G * H);
  u16*    csr       = (u16*)   carve(sizeof(u16)    * (size_t)(E+N));
  float4* y0        = (float4*)carve(sizeof(float4) * (size_t)N);
  u16*    ybufA     = (u16*)   carve(sizeof(u16)    * (size_t)N * H);
  u16*    ybufB     = (u16*)   carve(sizeof(u16)    * (size_t)N * H);
  u16*    wp2       = (u16*)   carve(sizeof(u16)    * 16384);
  u16*    wp3       = (u16*)   carve(sizeof(u16)    * 16384);

  // cooperative grid size: as many co-resident blocks as the device allows (capped)
  int maxb = 0;
  if (hipOccupancyMaxActiveBlocksPerMultiprocessor(&maxb, (const void*)k_mega, 256, 0) != hipSuccess || maxb < 1)
    maxb = 4;
  int dev = 0;
  hipGetDevice(&dev);
  hipDeviceProp_t prop;
  int cus = 256;
  if (hipGetDeviceProperties(&prop, dev) == hipSuccess && prop.multiProcessorCount > 0)
    cus = prop.multiProcessorCount;
  long long gridll = (long long)maxb * cus;
  if (gridll > 2048) gridll = 2048;
  if (gridll < 64)   gridll = 64;
  unsigned grid = (unsigned)gridll;

  void* kargs[] = {
    (void*)&pos, (void*)&ei, (void*)&batch,
    (void*)&W1, (void*)&b1, (void*)&W2, (void*)&b2,
    (void*)&W3, (void*)&b3, (void*)&Wl1, (void*)&bl1,
    (void*)&Wl2, (void*)&bl2, (void*)&out,
    (void*)&N, (void*)&E, (void*)&G,
    (void*)&deg, (void*)&rank, (void*)&start, (void*)&dinv, (void*)&alloc_ctr,
    (void*)&gb, (void*)&gsum, (void*)&csr, (void*)&y0,
    (void*)&ybufA, (void*)&ybufB, (void*)&wp2, (void*)&wp3
  };
  hipLaunchCooperativeKernel((const void*)k_mega, dim3(grid), dim3(256), kargs, 0, stream);
}

// Round 13
// 253.977 us; speedup vs baseline: 2.6675x; 2.6675x over previous
//
#include <hip/hip_runtime.h>

#define H 128
#define LSTRIDE 136   // LDS row stride in bf16 elems: 272B, 16B-aligned, 2-way bank (free)
#define PSTR 132      // pool stride in floats: rl*132 -> bank offset rl*4, 2-way (free)
typedef unsigned int uint32;
typedef unsigned short ushort16;
typedef __attribute__((ext_vector_type(8))) short bf16x8;
typedef __attribute__((ext_vector_type(4))) float f32x4;

static __device__ __forceinline__ ushort16 f2bf(float f){
  uint32 u = __float_as_uint(f);
  uint32 r = (u + 0x7fff + ((u >> 16) & 1)) >> 16;   // RNE bf16 (finite values)
  return (ushort16)r;
}
static __device__ __forceinline__ float bflo(uint32 u){ return __uint_as_float(u << 16); }
static __device__ __forceinline__ float bfhi(uint32 u){ return __uint_as_float(u & 0xffff0000u); }

// fused setup: deg=0, gsum=0, gb[0..G]; last 16 blocks also prep W2/W3 into MFMA B-frag bf16
__global__ __launch_bounds__(256) void k_setup(int* __restrict__ deg, float* __restrict__ gsum,
                                               const int* __restrict__ batch, int n, int G,
                                               int* __restrict__ gb, int SB,
                                               const float* __restrict__ W2, const float* __restrict__ W3,
                                               ushort16* __restrict__ wp2, ushort16* __restrict__ wp3){
  int b = blockIdx.x;
  if (b < SB){
    int i = b*256 + threadIdx.x;
    if (i < n) deg[i] = 0;
    if (i < G*H) gsum[i] = 0.f;
    if (i <= G){
      int lo = 0, hi = n;
      while (lo < hi){ int m = (lo + hi) >> 1; if (batch[m] < i) lo = m + 1; else hi = m; }
      gb[i] = lo;
    }
  } else {
    int gid = (b - SB)*256 + threadIdx.x;   // 0..4095
    const float* W = (gid < 2048) ? W2 : W3;
    ushort16* wp   = (gid < 2048) ? wp2 : wp3;
    int tid = gid & 2047;
    int frag = tid >> 6, lane = tid & 63;
    int kt = frag >> 3, ct = frag & 7;
    int m = lane & 15, quad = lane >> 4;
    const float* wrow = &W[(kt*32 + quad*8)*H + ct*16 + m];
    ushort16 vals[8];
    #pragma unroll
    for (int j = 0; j < 8; j++) vals[j] = f2bf(wrow[j*H]);
    uint4 o;
    o.x = (uint32)vals[0] | ((uint32)vals[1] << 16);
    o.y = (uint32)vals[2] | ((uint32)vals[3] << 16);
    o.z = (uint32)vals[4] | ((uint32)vals[5] << 16);
    o.w = (uint32)vals[6] | ((uint32)vals[7] << 16);
    *(uint4*)&wp[(size_t)tid*8] = o;
  }
}

// rank[e] = position of edge e within its dst bucket (ushort: max deg << 65536)
__global__ __launch_bounds__(256) void k_count_rank(const int* __restrict__ dst, int E,
                                                    int* __restrict__ deg, unsigned short* __restrict__ rank){
  int i = blockIdx.x*256 + threadIdx.x;
  if (i < E) rank[i] = (unsigned short)atomicAdd(&deg[dst[i]], 1);
}

// ---- scan of (deg+1) -> block-local offsets, block totals to bsum, dinv ----
__global__ __launch_bounds__(256) void k_scan1(const int* __restrict__ deg, int n,
      int* __restrict__ offsets, int* __restrict__ bsum, float* __restrict__ dinv){
  __shared__ int sh[256];
  int b = blockIdx.x, t = threadIdx.x;
  int base = b*1024 + t*4;
  bool i0 = base+0 < n, i1 = base+1 < n, i2 = base+2 < n, i3 = base+3 < n;
  int d0=0,d1=0,d2=0,d3=0;
  if (i3){ int4 v = *(const int4*)&deg[base]; d0=v.x; d1=v.y; d2=v.z; d3=v.w; }
  else {
    if (i0) d0 = deg[base+0];
    if (i1) d1 = deg[base+1];
    if (i2) d2 = deg[base+2];
  }
  int e0 = i0? d0+1:0, e1 = i1? d1+1:0, e2 = i2? d2+1:0, e3 = i3? d3+1:0;   // +1 self-loop
  sh[t] = e0+e1+e2+e3;
  __syncthreads();
  for (int off=1; off<256; off<<=1){
    int v = sh[t];
    int add = (t>=off)? sh[t-off] : 0;
    __syncthreads();
    sh[t] = v+add;
    __syncthreads();
  }
  int o0 = (t==0)?0:sh[t-1];
  int o1 = o0+e0, o2 = o1+e1, o3 = o2+e2;
  if (i0){ offsets[base+0]=o0; dinv[base+0]=rsqrtf((float)(d0+1)); }
  if (i1){ offsets[base+1]=o1; dinv[base+1]=rsqrtf((float)(d1+1)); }
  if (i2){ offsets[base+2]=o2; dinv[base+2]=rsqrtf((float)(d2+1)); }
  if (i3){ offsets[base+3]=o3; dinv[base+3]=rsqrtf((float)(d3+1)); }
  if (t==255) bsum[b] = sh[255];
}

// add block prefix (in-wave scan of bsum, B <= 64); ALSO emits y0 = dinv*pos (prescale fused).
// Last block writes offsets[n].
__global__ __launch_bounds__(256) void k_scan3b(int* __restrict__ offsets, int n,
                                                const int* __restrict__ bsum, int B,
                                                const float* __restrict__ pos, const float* __restrict__ dinv,
                                                float4* __restrict__ y0){
  __shared__ int sh[2];
  int b = blockIdx.x, t = threadIdx.x;
  if (t < 64){
    int v   = (t < B)? bsum[t] : 0;
    int pre = (t < b)? v : 0;
    int tot = v;
    for (int o=1; o<64; o<<=1){ pre += __shfl_xor(pre,o); tot += __shfl_xor(tot,o); }
    if (t == 0){ sh[0] = pre; sh[1] = tot; }
  }
  __syncthreads();
  int add = sh[0];
  int base = b*1024 + t*4;
  if (base+3 < n){
    int4 v = *(int4*)&offsets[base];
    v.x+=add; v.y+=add; v.z+=add; v.w+=add;
    *(int4*)&offsets[base] = v;
  } else {
    #pragma unroll
    for (int k=0;k<4;k++){ int i=base+k; if (i<n) offsets[i]+=add; }
  }
  #pragma unroll
  for (int k=0;k<4;k++){
    int i = base+k;
    if (i < n){
      float d = dinv[i];
      y0[i] = make_float4(pos[3*i]*d, pos[3*i+1]*d, pos[3*i+2]*d, 0.f);
    }
  }
  if (b == B-1 && t == 255) offsets[n] = sh[1];
}

// atomic-free CSR fill (ushort payload): edge e -> slot offsets[dst]+1+rank[e]; self-loop at offsets[i]
__global__ __launch_bounds__(256) void k_fill2(const int* __restrict__ src, const int* __restrict__ dst,
            int E, int n, const int* __restrict__ offsets, const unsigned short* __restrict__ rank,
            unsigned short* __restrict__ csr_src){
  int i = blockIdx.x*256 + threadIdx.x;
  if (i < E){
    csr_src[offsets[dst[i]] + 1 + rank[i]] = (unsigned short)src[i];
  } else if (i < E + n){
    int j = i - E;
    csr_src[offsets[j]] = (unsigned short)j;
  }
}

// Fused layer 1: per node, a = dinv * sum_src y0[src] (3-wide gather), then
// y1[node,c] = bf16( dinv * relu(a . W1[:,c] + b1[c]) ) for all 128 cols (W1/b1 wave-uniform).
__global__ __launch_bounds__(256) void k_layer1(const float4* __restrict__ y0, const int* __restrict__ offsets,
      const unsigned short* __restrict__ csr_src, const float* __restrict__ dinv,
      const float* __restrict__ W1, const float* __restrict__ b1,
      ushort16* __restrict__ y1, int n){
  int node = blockIdx.x*256 + threadIdx.x;
  if (node >= n) return;
  int lo = offsets[node], hi = offsets[node+1];
  float x=0.f, y=0.f, z=0.f;
  int e = lo;
  for (; e+2 <= hi; e += 2){
    int s0 = csr_src[e], s1 = csr_src[e+1];
    float4 v0 = y0[s0], v1 = y0[s1];
    x += v0.x + v1.x; y += v0.y + v1.y; z += v0.z + v1.z;
  }
  if (e < hi){ float4 v = y0[csr_src[e]]; x += v.x; y += v.y; z += v.z; }
  float dn = dinv[node];
  x *= dn; y *= dn; z *= dn;
  ushort16* rowp = &y1[(size_t)node*H];
  for (int c8 = 0; c8 < 16; c8++){
    float4 wa0 = *(const float4*)&W1[c8*8];
    float4 wa1 = *(const float4*)&W1[c8*8+4];
    float4 wb0 = *(const float4*)&W1[H + c8*8];
    float4 wb1 = *(const float4*)&W1[H + c8*8+4];
    float4 wc0 = *(const float4*)&W1[2*H + c8*8];
    float4 wc1 = *(const float4*)&W1[2*H + c8*8+4];
    float4 bb0 = *(const float4*)&b1[c8*8];
    float4 bb1 = *(const float4*)&b1[c8*8+4];
    float o0 = fmaxf(x*wa0.x + y*wb0.x + z*wc0.x + bb0.x, 0.f) * dn;
    float o1 = fmaxf(x*wa0.y + y*wb0.y + z*wc0.y + bb0.y, 0.f) * dn;
    float o2 = fmaxf(x*wa0.z + y*wb0.z + z*wc0.z + bb0.z, 0.f) * dn;
    float o3 = fmaxf(x*wa0.w + y*wb0.w + z*wc0.w + bb0.w, 0.f) * dn;
    float o4 = fmaxf(x*wa1.x + y*wb1.x + z*wc1.x + bb1.x, 0.f) * dn;
    float o5 = fmaxf(x*wa1.y + y*wb1.y + z*wc1.y + bb1.y, 0.f) * dn;
    float o6 = fmaxf(x*wa1.z + y*wb1.z + z*wc1.z + bb1.z, 0.f) * dn;
    float o7 = fmaxf(x*wa1.w + y*wb1.w + z*wc1.w + bb1.w, 0.f) * dn;
    uint4 o;
    o.x = (uint32)f2bf(o0) | ((uint32)f2bf(o1) << 16);
    o.y = (uint32)f2bf(o2) | ((uint32)f2bf(o3) << 16);
    o.z = (uint32)f2bf(o4) | ((uint32)f2bf(o5) << 16);
    o.w = (uint32)f2bf(o6) | ((uint32)f2bf(o7) << 16);
    *(uint4*)&rowp[c8*8] = o;
  }
}

// Fused aggregate + MFMA dense (full gather parallelism: 16 nodes/block, 16 lanes/node, one pass).
// POOL=0: yout tile staged in LDS then coalesced 16B/lane bf16 stores (layer 2)
// POOL=1: relu(aW+b) -> LDS tile -> parallel segmented atomicAdd into gsum (layer 3 + pool numerator)
template<int POOL>
__global__ __launch_bounds__(256) void k_aggdense(const ushort16* __restrict__ y, const int* __restrict__ offsets,
      const unsigned short* __restrict__ csr_src, const float* __restrict__ dinv, const ushort16* __restrict__ wp,
      const float* __restrict__ bias,
      ushort16* __restrict__ yout, const int* __restrict__ batch, float* __restrict__ gsum, int n){
  __shared__ unsigned short As[16*LSTRIDE];          // 4352 B
  __shared__ float pool[POOL ? 16*PSTR : 1];         // 8448 B (POOL only)
  __shared__ unsigned short outs[POOL ? 1 : 16*PSTR];// 4224 B (non-POOL: staged bf16 out tile)
  __shared__ int sbatch[POOL ? 16 : 1];
  int tid = threadIdx.x;
  int node16 = blockIdx.x*16;
  int nl = tid >> 4;                 // local node 0..15
  int node = node16 + nl;
  int f8 = (tid & 15) * 8;

  if (POOL && tid < 16) sbatch[tid] = (node16 + tid < n) ? batch[node16 + tid] : -1;

  // ---- phase A: aggregate (identical parallelism to standalone agg128) ----
  float a0=0,a1=0,a2=0,a3=0,a4=0,a5=0,a6=0,a7=0;
  float dn = 0.f;
  #define ADDU(u) { a0+=bflo(u.x); a1+=bfhi(u.x); a2+=bflo(u.y); a3+=bfhi(u.y); \
                    a4+=bflo(u.z); a5+=bfhi(u.z); a6+=bflo(u.w); a7+=bfhi(u.w); }
  if (node < n){
    int lo = offsets[node], hi = offsets[node+1];
    int e = lo;
    for (; e+8 <= hi; e += 8){
      int s0=csr_src[e],   s1=csr_src[e+1], s2=csr_src[e+2], s3=csr_src[e+3];
      int s4=csr_src[e+4], s5=csr_src[e+5], s6=csr_src[e+6], s7=csr_src[e+7];
      uint4 u0 = *(const uint4*)&y[(size_t)s0*H + f8];
      uint4 u1 = *(const uint4*)&y[(size_t)s1*H + f8];
      uint4 u2 = *(const uint4*)&y[(size_t)s2*H + f8];
      uint4 u3 = *(const uint4*)&y[(size_t)s3*H + f8];
      uint4 u4 = *(const uint4*)&y[(size_t)s4*H + f8];
      uint4 u5 = *(const uint4*)&y[(size_t)s5*H + f8];
      uint4 u6 = *(const uint4*)&y[(size_t)s6*H + f8];
      uint4 u7 = *(const uint4*)&y[(size_t)s7*H + f8];
      ADDU(u0); ADDU(u1); ADDU(u2); ADDU(u3);
      ADDU(u4); ADDU(u5); ADDU(u6); ADDU(u7);
    }
    for (; e < hi; e++){
      int s = csr_src[e];
      uint4 u = *(const uint4*)&y[(size_t)s*H + f8];
      ADDU(u);
    }
    dn = dinv[node];
  }
  #undef ADDU
  uint4 o;
  o.x = (uint32)f2bf(a0*dn) | ((uint32)f2bf(a1*dn) << 16);
  o.y = (uint32)f2bf(a2*dn) | ((uint32)f2bf(a3*dn) << 16);
  o.z = (uint32)f2bf(a4*dn) | ((uint32)f2bf(a5*dn) << 16);
  o.w = (uint32)f2bf(a6*dn) | ((uint32)f2bf(a7*dn) << 16);
  *(uint4*)&As[nl*LSTRIDE + f8] = o;
  __syncthreads();

  // ---- phase B: MFMA — wave w handles col-tiles {2w, 2w+1} over the 16 staged rows ----
  int wave = tid >> 6;
  int lane = tid & 63;
  int m = lane & 15, quad = lane >> 4;
  f32x4 acc0 = {0.f,0.f,0.f,0.f}, acc1 = {0.f,0.f,0.f,0.f};
  int ct0 = wave*2, ct1 = wave*2 + 1;
  #pragma unroll
  for (int kt = 0; kt < 4; kt++){
    bf16x8 af = *(const bf16x8*)&As[m*LSTRIDE + kt*32 + quad*8];
    bf16x8 b0 = *(const bf16x8*)&wp[(size_t)((kt*8+ct0)*64 + lane)*8];
    bf16x8 b1 = *(const bf16x8*)&wp[(size_t)((kt*8+ct1)*64 + lane)*8];
    acc0 = __builtin_amdgcn_mfma_f32_16x16x32_bf16(af, b0, acc0, 0, 0, 0);
    acc1 = __builtin_amdgcn_mfma_f32_16x16x32_bf16(af, b1, acc1, 0, 0, 0);
  }
  // C/D layout: col = ct*16 + m, row (in tile) = quad*4 + r
  #pragma unroll
  for (int j = 0; j < 2; j++){
    int ct = wave*2 + j;
    int col = ct*16 + m;
    float bv = bias[col];
    f32x4 ac = j ? acc1 : acc0;
    #pragma unroll
    for (int r = 0; r < 4; r++){
      int rl = quad*4 + r;
      int orow = node16 + rl;
      if (orow < n){
        float v = fmaxf(ac[r] + bv, 0.f);
        if (POOL) pool[rl*PSTR + col] = v;                            // one lane per (row,col)
        else      outs[rl*PSTR + col] = f2bf(v * dinv[orow]);
      }
    }
  }
  __syncthreads();
  if (POOL){
    // parallel segmented tail: 256 threads = 128 cols x 2 row-halves
    int col = tid & 127;
    int half = tid >> 7;
    float run = 0.f; int gprev = -1;
    for (int r = half*8; r < half*8 + 8; r++){
      int g = sbatch[r];
      if (g < 0) break;            // tail rows only
      if (g != gprev){
        if (gprev >= 0) atomicAdd(&gsum[gprev*H + col], run);
        run = 0.f; gprev = g;
      }
      run += pool[r*PSTR + col];
    }
    if (gprev >= 0) atomicAdd(&gsum[gprev*H + col], run);
  } else {
    // coalesced store: thread t writes row t>>4, 8 bf16 at (t&15)*8
    int row = tid >> 4;
    int orow = node16 + row;
    if (orow < n){
      const unsigned short* sp = &outs[row*PSTR + f8];
      uint4 v;
      v.x = (uint32)sp[0] | ((uint32)sp[1] << 16);
      v.y = (uint32)sp[2] | ((uint32)sp[3] << 16);
      v.z = (uint32)sp[4] | ((uint32)sp[5] << 16);
      v.w = (uint32)sp[6] | ((uint32)sp[7] << 16);
      *(uint4*)&yout[(size_t)orow*H + f8] = v;
    }
  }
}

// MLP head: relu((gsum/cnt) @ Wl1 + bl1) @ Wl2 + bl2
__global__ __launch_bounds__(64) void k_head(const float* __restrict__ gsum, const int* __restrict__ gb,
            const float* __restrict__ Wl1, const float* __restrict__ bl1,
            const float* __restrict__ Wl2, const float* __restrict__ bl2,
            float* __restrict__ out){
  int g = blockIdx.x;
  int t = threadIdx.x;
  __shared__ float gs[H];
  __shared__ float h1[64];
  float inv = 1.f / fmaxf((float)(gb[g+1] - gb[g]), 1.f);
  gs[t]      = gsum[g*H + t]      * inv;
  gs[64 + t] = gsum[g*H + 64 + t] * inv;
  __syncthreads();
  float acc = bl1[t];
  for (int k = 0; k < H; k++) acc += gs[k] * Wl1[k*64 + t];
  h1[t] = fmaxf(acc, 0.f);
  __syncthreads();
  if (t < 10){
    float o = bl2[t];
    for (int j = 0; j < 64; j++) o += h1[j] * Wl2[j*10 + t];
    out[g*10 + t] = o;
  }
}

extern "C" void kernel_launch(void* const* d_in, const int* in_sizes, int n_in,
                              void* d_out, int out_size, void* d_ws, size_t ws_size,
                              hipStream_t stream){
  const float* pos = (const float*)d_in[0];
  const int*  ei   = (const int*)d_in[1];
  const int*  batch= (const int*)d_in[2];
  const float* W1 = (const float*)d_in[3];
  const float* b1 = (const float*)d_in[4];
  const float* W2 = (const float*)d_in[5];
  const float* b2 = (const float*)d_in[6];
  const float* W3 = (const float*)d_in[7];
  const float* b3 = (const float*)d_in[8];
  const float* Wl1 = (const float*)d_in[9];
  const float* bl1 = (const float*)d_in[10];
  const float* Wl2 = (const float*)d_in[11];
  const float* bl2 = (const float*)d_in[12];
  float* out = (float*)d_out;

  int N = in_sizes[0] / 3;     // 50000 (< 65536 required for ushort CSR)
  int E = in_sizes[1] / 2;     // 800000
  int G = out_size / 10;       // 64
  int B = (N + 1023) / 1024;   // 49, must be <= 64 for k_scan3b
  int SB = (N + 255) / 256;    // setup blocks

  // workspace carve (~30 MB)
  char* p = (char*)d_ws;
  auto carve = [&](size_t bytes)->char* { char* q = p; p += (bytes + 255) & ~(size_t)255; return q; };
  int*            deg     = (int*)     carve(sizeof(int)    * (size_t)N);
  int*            offsets = (int*)     carve(sizeof(int)    * (size_t)(N+1));
  float*          dinv    = (float*)   carve(sizeof(float)  * (size_t)N);
  int*            bsum    = (int*)     carve(sizeof(int)    * 256);
  int*            gb      = (int*)     carve(sizeof(int)    * (size_t)(G+1));
  float*          gsum    = (float*)   carve(sizeof(float)  * (size_t)G * H);
  unsigned short* csr_src = (unsigned short*)carve(sizeof(unsigned short) * (size_t)(E+N));
  unsigned short* rank    = (unsigned short*)carve(sizeof(unsigned short) * (size_t)E);
  float4*         y0      = (float4*)  carve(sizeof(float4) * (size_t)N);
  ushort16*       ybufA   = (ushort16*)carve(sizeof(ushort16) * (size_t)N * H);
  ushort16*       ybufB   = (ushort16*)carve(sizeof(ushort16) * (size_t)N * H);
  ushort16*       wp2     = (ushort16*)carve(sizeof(ushort16) * 16384);
  ushort16*       wp3     = (ushort16*)carve(sizeof(ushort16) * 16384);

  const int* src = ei;
  const int* dst = ei + E;

  hipLaunchKernelGGL(k_setup, dim3(SB + 16), dim3(256), 0, stream,
                     deg, gsum, batch, N, G, gb, SB, W2, W3, wp2, wp3);

  hipLaunchKernelGGL(k_count_rank, dim3((E+255)/256),   dim3(256), 0, stream, dst, E, deg, rank);
  hipLaunchKernelGGL(k_scan1,      dim3(B),             dim3(256), 0, stream, deg, N, offsets, bsum, dinv);
  hipLaunchKernelGGL(k_scan3b,     dim3(B),             dim3(256), 0, stream, offsets, N, bsum, B, pos, dinv, y0);
  hipLaunchKernelGGL(k_fill2,      dim3((E+N+255)/256), dim3(256), 0, stream, src, dst, E, N, offsets, rank, csr_src);

  // layer 1 (aggregate-first 3-wide gather + fused 3->128 dense)
  hipLaunchKernelGGL(k_layer1, dim3((N+255)/256), dim3(256), 0, stream, y0, offsets, csr_src, dinv, W1, b1, ybufA, N);

  // layer 2 (fused aggregate + MFMA, bf16 y out via LDS-staged coalesced store)
  hipLaunchKernelGGL(k_aggdense<0>, dim3((N+15)/16), dim3(256), 0, stream,
                     ybufA, offsets, csr_src, dinv, wp2, b2, ybufB, (const int*)nullptr, (float*)nullptr, N);

  // layer 3 (fused aggregate + MFMA + mean-pool numerator into gsum)
  hipLaunchKernelGGL(k_aggdense<1>, dim3((N+15)/16), dim3(256), 0, stream,
                     ybufB, offsets, csr_src, dinv, wp3, b3, (ushort16*)nullptr, batch, gsum, N);

  hipLaunchKernelGGL(k_head, dim3(G), dim3(64), 0, stream, gsum, gb, Wl1, bl1, Wl2, bl2, out);
}